// Round 16
// baseline (144.258 us; speedup 1.0000x reference)
//
#include <hip/hip_runtime.h>

// AdditiveAttention: b=4, n_q=64, s=1024, Q_DIM=K_DIM=HID=VDIM=512, f32 in/out.
// R16: R13 (best, 117.7) + reduce folded into av_gemm via LAST-BLOCK-PER-GROUP
// reduction (no grid barrier — R12's skew can't happen; only the 8th arriver
// of each (vt,b) group reduces its 64x64 region). 4 nodes: convert, proj,
// scores (zeroes group counters), av+reduce.

static constexpr int SLEN = 1024;
static constexpr int DIM  = 512;
static constexpr float TANH_SCALE = 2.885390081777927f;  // 2*log2(e)

typedef __attribute__((ext_vector_type(8))) short bf16x8;
typedef __attribute__((ext_vector_type(4))) float f32x4;

__device__ __forceinline__ float fast_exp2(float x) { return __builtin_amdgcn_exp2f(x); }
__device__ __forceinline__ float fast_rcp(float x)  { return __builtin_amdgcn_rcpf(x); }

__device__ __forceinline__ unsigned int f2bf(float f) {
    unsigned int u = __float_as_uint(f);
    u += 0x7FFF + ((u >> 16) & 1);   // RNE
    return u >> 16;
}

__device__ __forceinline__ void async_copy16(const void* g, void* l) {
    __builtin_amdgcn_global_load_lds(
        (const __attribute__((address_space(1))) unsigned int*)g,
        (__attribute__((address_space(3))) unsigned int*)l, 16, 0, 0);
}

// f32 -> bf16 pre-convert: queries (131072), keys (2097152), W1 (524288) elems.
// (Kept as its own node: R15 showed fusing this into proj costs ~7 µs — proj's
// bf16 DMA staging halves its traffic and hides latency.)
__global__ __launch_bounds__(256) void convert_bf16(
    const float* __restrict__ q, const float* __restrict__ k,
    const float* __restrict__ w, unsigned short* __restrict__ qb,
    unsigned short* __restrict__ kb, unsigned short* __restrict__ wb)
{
    int id = blockIdx.x * 256 + threadIdx.x;
    const float* src; unsigned short* dst; int off;
    if (id < 32768)        { src = q; dst = qb; off = id; }
    else if (id < 557056)  { src = k; dst = kb; off = id - 32768; }
    else                   { src = w; dst = wb; off = id - 557056; }
    float4 v = ((const float4*)src)[off];
    ushort4 o;
    o.x = (unsigned short)f2bf(v.x); o.y = (unsigned short)f2bf(v.y);
    o.z = (unsigned short)f2bf(v.z); o.w = (unsigned short)f2bf(v.w);
    ((ushort4*)dst)[off] = o;
}

// Fused q_proj/k_proj GEMM, bf16 MFMA, global_load_lds staging.
// E[m][n] = exp2( (sum_k A[m][k]*W1[n][col_off+k] + bias[n]) * TANH_SCALE )
// blocks 0..511: k_proj -> Ek; 512..543: q_proj -> Eq. Tile 64x64, BK=64.
// LDS rows 128 B DMA-packed; XOR swizzle keeps ds_read_b128 <=2-way.
__global__ __launch_bounds__(256) void proj_mfma(
    const unsigned short* __restrict__ qb, const unsigned short* __restrict__ kb,
    const unsigned short* __restrict__ wb, const float* __restrict__ b1,
    float* __restrict__ qp, float* __restrict__ kp)
{
    __shared__ __align__(16) unsigned short As[64][64];
    __shared__ __align__(16) unsigned short Ws[64][64];

    const int bx = blockIdx.x;
    const unsigned short* A; float* C; const float* bias; int mb, nb, col_off;
    if (bx < 512) {
        A = kb; C = kp; bias = b1; col_off = 512;
        mb = (bx >> 3) * 64; nb = (bx & 7) * 64;
    } else {
        int b2 = bx - 512;
        A = qb; C = qp; bias = nullptr; col_off = 0;
        mb = (b2 >> 3) * 64; nb = (b2 & 7) * 64;
    }

    const int t = threadIdx.x;
    const int l = t & 63;
    const int wv = t >> 6;
    const int wm = (wv & 1) * 32;
    const int wn = (wv >> 1) * 32;
    const int lane16 = l & 15;
    const int quad   = l >> 4;
    const int r8   = l >> 3;
    const int schk = (l & 7) ^ r8;

    f32x4 acc[2][2] = {{{0.f,0.f,0.f,0.f},{0.f,0.f,0.f,0.f}},
                       {{0.f,0.f,0.f,0.f},{0.f,0.f,0.f,0.f}}};

    for (int kc = 0; kc < DIM; kc += 64) {
#pragma unroll
        for (int i = 0; i < 2; ++i) {
            int rbase = wv * 16 + i * 8;
            async_copy16(A + (size_t)(mb + rbase + r8) * DIM + kc + schk * 8, &As[rbase][0]);
            async_copy16(wb + (size_t)(nb + rbase + r8) * 1024 + col_off + kc + schk * 8, &Ws[rbase][0]);
        }
        __syncthreads();

#pragma unroll
        for (int ks = 0; ks < 2; ++ks) {
            int cc = ks * 4 + quad;
            int sw = (cc ^ (lane16 & 7)) << 3;
            bf16x8 a0  = *(const bf16x8*)&As[wm + lane16][sw];
            bf16x8 a1  = *(const bf16x8*)&As[wm + 16 + lane16][sw];
            bf16x8 b0  = *(const bf16x8*)&Ws[wn + lane16][sw];
            bf16x8 b1v = *(const bf16x8*)&Ws[wn + 16 + lane16][sw];
            acc[0][0] = __builtin_amdgcn_mfma_f32_16x16x32_bf16(a0, b0,  acc[0][0], 0, 0, 0);
            acc[0][1] = __builtin_amdgcn_mfma_f32_16x16x32_bf16(a0, b1v, acc[0][1], 0, 0, 0);
            acc[1][0] = __builtin_amdgcn_mfma_f32_16x16x32_bf16(a1, b0,  acc[1][0], 0, 0, 0);
            acc[1][1] = __builtin_amdgcn_mfma_f32_16x16x32_bf16(a1, b1v, acc[1][1], 0, 0, 0);
        }
        __syncthreads();
    }

#pragma unroll
    for (int mi = 0; mi < 2; ++mi) {
#pragma unroll
        for (int ni = 0; ni < 2; ++ni) {
            int col = nb + wn + 16 * ni + lane16;
            float bv = bias ? bias[col] : 0.0f;
#pragma unroll
            for (int r = 0; r < 4; ++r) {
                int row = mb + wm + 16 * mi + quad * 4 + r;
                C[(size_t)row * DIM + col] = fast_exp2((acc[mi][ni][r] + bv) * TANH_SCALE);
            }
        }
    }
}

// th[half][b,q,s] = -TANH_SCALE * sum_{h in half} w2[h]/(1 + Eq[q][h]*Ek[s][h])
// d = fma(Eq,Ek,1); paired rcp. q-row in registers (broadcast loads), w2 via
// wave-uniform s_load; only k through LDS. Tile 16q x 32s. Grid (32, 8, 4).
// Block (0,0,0) zeroes the 32 av group counters (ordered by graph edge).
__global__ __launch_bounds__(256, 4) void scores_kernel(
    const float* __restrict__ qp, const float* __restrict__ kp,
    const float* __restrict__ w2, float* __restrict__ th,
    unsigned int* __restrict__ counters)
{
    __shared__ __align__(16) float ks[32][68];
    const int t     = threadIdx.x;
    if (blockIdx.x == 0 && blockIdx.y == 0 && blockIdx.z == 0 && t < 32)
        counters[t] = 0;
    const int sb    = blockIdx.x * 32;
    const int qt    = blockIdx.y & 3;
    const int half  = blockIdx.y >> 2;
    const int kbase = half * 256;
    const int qrow0 = blockIdx.z * 64 + qt * 16;
    const int krow0 = blockIdx.z * 1024 + sb;
    float* thh = th + (size_t)half * 256 * SLEN;

    const int tq = t >> 4;
    const int ts = t & 15;
    const float* qrow = qp + (size_t)(qrow0 + tq) * DIM + kbase;
    const float* w2b  = w2 + kbase;
    float a00 = 0.f, a01 = 0.f, a10 = 0.f, a11 = 0.f;

    for (int kc = 0; kc < 256; kc += 64) {
#pragma unroll
        for (int rr = 0; rr < 2; ++rr) {
            int idx = t + rr * 256;
            int r = idx >> 4, g = (idx & 15) << 2;
            *(float4*)&ks[r][g] = *(const float4*)(kp + (size_t)(krow0 + r) * DIM + kbase + kc + g);
        }
        float4 qreg[16];
#pragma unroll
        for (int i = 0; i < 16; ++i)
            qreg[i] = *(const float4*)(qrow + kc + (i << 2));
        __syncthreads();
#pragma unroll
        for (int k4 = 0; k4 < 16; ++k4) {
            float4 qv = qreg[k4];
            float4 k0 = *(const float4*)&ks[ts][k4 << 2];
            float4 k1 = *(const float4*)&ks[ts + 16][k4 << 2];
            float4 wv = *(const float4*)(w2b + kc + (k4 << 2));
            {
                float d0 = fmaf(qv.x, k0.x, 1.0f);
                float d1 = fmaf(qv.y, k0.y, 1.0f);
                a00 = fmaf(fmaf(wv.x, d1, wv.y * d0), fast_rcp(d0 * d1), a00);
                float d2 = fmaf(qv.z, k0.z, 1.0f);
                float d3 = fmaf(qv.w, k0.w, 1.0f);
                a01 = fmaf(fmaf(wv.z, d3, wv.w * d2), fast_rcp(d2 * d3), a01);
            }
            {
                float d0 = fmaf(qv.x, k1.x, 1.0f);
                float d1 = fmaf(qv.y, k1.y, 1.0f);
                a10 = fmaf(fmaf(wv.x, d1, wv.y * d0), fast_rcp(d0 * d1), a10);
                float d2 = fmaf(qv.z, k1.z, 1.0f);
                float d3 = fmaf(qv.w, k1.w, 1.0f);
                a11 = fmaf(fmaf(wv.z, d3, wv.w * d2), fast_rcp(d2 * d3), a11);
            }
        }
        __syncthreads();
    }
    thh[(size_t)(qrow0 + tq) * SLEN + sb + ts]      = -TANH_SCALE * (a00 + a01);
    thh[(size_t)(qrow0 + tq) * SLEN + sb + ts + 16] = -TANH_SCALE * (a10 + a11);
}

// pt[kt][b*64+q][v] = sum over 128-s chunk of e*values, e = exp2(th0+th1)
// inline during staging. EVERY block writes its own row-sum copy
// sums_p[(vt*8+kt)*256+row]. Then release-fence + per-(vt,b)-group atomic
// arrival; the 8th arriver reduces its 64x64 out region and normalizes.
// Grid (8 vt, 8 kt, 4 b) = 256 blocks; no block ever waits.
__global__ __launch_bounds__(256) void av_gemm(
    const float* __restrict__ th, const float* __restrict__ values,
    float* __restrict__ pt, float* __restrict__ sums_p,
    unsigned int* __restrict__ counters, float* __restrict__ out)
{
    __shared__ __align__(16) float As[32][68];
    __shared__ __align__(16) float Bs[32][68];
    const int t  = threadIdx.x;
    const int vt = blockIdx.x;
    const int nb = vt * 64;
    const int kt = blockIdx.y;
    const int kb = kt * 128;
    const int b  = blockIdx.z;
    const int tx = t & 15, ty = t >> 4;
    float acc[4][4] = {};
    float rsum[2] = {0.f, 0.f};
    for (int kc = 0; kc < 128; kc += 32) {
        const int k0 = kb + kc;
#pragma unroll
        for (int r = 0; r < 2; ++r) {
            int idx = t + r * 256;
            int m   = idx >> 3;
            int k4  = (idx & 7) << 2;
            size_t base = (size_t)(b * 64 + m) * SLEN + k0 + k4;
            float4 t0 = *(const float4*)(th + base);
            float4 t1 = *(const float4*)(th + 262144 + base);
            float4 e;
            e.x = fast_exp2(t0.x + t1.x);
            e.y = fast_exp2(t0.y + t1.y);
            e.z = fast_exp2(t0.z + t1.z);
            e.w = fast_exp2(t0.w + t1.w);
            As[k4 + 0][m] = e.x; As[k4 + 1][m] = e.y;
            As[k4 + 2][m] = e.z; As[k4 + 3][m] = e.w;
            rsum[r] += e.x + e.y + e.z + e.w;
            int kk = idx >> 4;
            int g  = (idx & 15) << 2;
            *(float4*)&Bs[kk][g] =
                *(const float4*)(values + (size_t)(b * 1024 + k0 + kk) * DIM + nb + g);
        }
        __syncthreads();
#pragma unroll
        for (int k = 0; k < 32; ++k) {
            float4 a  = *(const float4*)&As[k][ty << 2];
            float4 bv = *(const float4*)&Bs[k][tx << 2];
            float am[4] = {a.x, a.y, a.z, a.w};
            float bn[4] = {bv.x, bv.y, bv.z, bv.w};
#pragma unroll
            for (int i = 0; i < 4; ++i)
#pragma unroll
                for (int j = 0; j < 4; ++j)
                    acc[i][j] = fmaf(am[i], bn[j], acc[i][j]);
        }
        __syncthreads();
    }
#pragma unroll
    for (int i = 0; i < 4; ++i) {
        int row = b * 64 + (ty << 2) + i;
        float4 o;
        o.x = acc[i][0]; o.y = acc[i][1]; o.z = acc[i][2]; o.w = acc[i][3];
        *(float4*)(pt + ((size_t)kt * 256 + row) * DIM + nb + (tx << 2)) = o;
    }
    // every block: own copy of the 128-s-chunk row sums
#pragma unroll
    for (int r = 0; r < 2; ++r) {
        float v = rsum[r];
        v += __shfl_xor(v, 1, 64);
        v += __shfl_xor(v, 2, 64);
        v += __shfl_xor(v, 4, 64);
        if ((t & 7) == 0) {
            int m = (t >> 3) + r * 32;
            sums_p[(vt * 8 + kt) * 256 + b * 64 + m] = v;
        }
    }

    // ---- last-block-per-group reduction (group = (vt,b), 8 kt members) ----
    __threadfence();                       // release pt/sums_p stores
    __syncthreads();                       // all threads fenced before arrival
    __shared__ unsigned int lastFlag;
    if (t == 0)
        lastFlag = (atomicAdd(&counters[(b << 3) | vt], 1u) == 7u);
    __syncthreads();
    if (lastFlag) {
        __threadfence();                   // acquire side
        const float4* p4 = (const float4*)pt;
        for (int j = t; j < 1024; j += 256) {
            int row  = j >> 4;             // 0..63
            int c4   = j & 15;             // 0..15
            int grow = b * 64 + row;
            float4 a = {0.f, 0.f, 0.f, 0.f};
            float s = 0.f;
#pragma unroll
            for (int k = 0; k < 8; ++k) {
                float4 v = p4[((size_t)k * 256 + grow) * 128 + vt * 16 + c4];
                a.x += v.x; a.y += v.y; a.z += v.z; a.w += v.w;
                s += sums_p[(vt * 8 + k) * 256 + grow];
            }
            float r = fast_rcp(s);
            a.x *= r; a.y *= r; a.z *= r; a.w *= r;
            ((float4*)out)[(size_t)grow * 128 + vt * 16 + c4] = a;
        }
    }
}

extern "C" void kernel_launch(void* const* d_in, const int* in_sizes, int n_in,
                              void* d_out, int out_size, void* d_ws, size_t ws_size,
                              hipStream_t stream) {
    const float* queries = (const float*)d_in[0];
    const float* keys    = (const float*)d_in[1];
    const float* values  = (const float*)d_in[2];
    const float* W1      = (const float*)d_in[3];
    const float* b1      = (const float*)d_in[4];
    const float* w2      = (const float*)d_in[5];
    float* out = (float*)d_out;

    float* qp     = (float*)d_ws;                   // 131072 f32 (Eq)
    float* kp     = qp + 131072;                    // 2097152 f32 (Ek)
    float* th     = kp + 2097152;                   // 2 x 262144 f32
    float* pt     = th + 2 * 262144;                // 8 x 131072 f32
    float* sums_p = pt + 8 * 131072;                // 64 x 256 f32
    unsigned int* counters = (unsigned int*)(sums_p + 16384);  // 32 u32
    unsigned short* qbf = (unsigned short*)(counters + 32);
    unsigned short* kbf = qbf + 131072;
    unsigned short* wbf = kbf + 2097152;
    (void)in_sizes; (void)n_in; (void)ws_size; (void)out_size;

    convert_bf16<<<dim3(2688), 256, 0, stream>>>(queries, keys, W1, qbf, kbf, wbf);
    proj_mfma<<<dim3(544), 256, 0, stream>>>(qbf, kbf, wbf, b1, qp, kp);
    scores_kernel<<<dim3(32, 8, 4), 256, 0, stream>>>(qp, kp, w2, th, counters);
    av_gemm<<<dim3(8, 8, 4), 256, 0, stream>>>(th, values, pt, sums_p, counters, out);
}

// Round 17
// 118.105 us; speedup vs baseline: 1.2214x; 1.2214x over previous
//
#include <hip/hip_runtime.h>

// AdditiveAttention: b=4, n_q=64, s=1024, Q_DIM=K_DIM=HID=VDIM=512, f32 in/out.
// R17 = R13 exact revert (verified best: 117.7 µs). 5 nodes:
//   convert (f32->bf16; kept separate — fusing into proj costs ~7 µs, R15),
//   proj (bf16 MFMA, global_load_lds DMA staging, epilogue writes Eq/Ek=exp2),
//   scores (2-way h-split, d=fma(Eq,Ek,1), paired rcp, q in regs, w2 s_load),
//   av (e=exp2 folded into staging + shuffle row-sums),
//   reduce (sum 8 kt-chunks + normalize).
// No atomics, no memsets, no cross-block sync (R11/R12/R16 fusions all regressed).

static constexpr int SLEN = 1024;
static constexpr int DIM  = 512;
static constexpr float TANH_SCALE = 2.885390081777927f;  // 2*log2(e)

typedef __attribute__((ext_vector_type(8))) short bf16x8;
typedef __attribute__((ext_vector_type(4))) float f32x4;

__device__ __forceinline__ float fast_exp2(float x) { return __builtin_amdgcn_exp2f(x); }
__device__ __forceinline__ float fast_rcp(float x)  { return __builtin_amdgcn_rcpf(x); }

__device__ __forceinline__ unsigned int f2bf(float f) {
    unsigned int u = __float_as_uint(f);
    u += 0x7FFF + ((u >> 16) & 1);   // RNE
    return u >> 16;
}

__device__ __forceinline__ void async_copy16(const void* g, void* l) {
    __builtin_amdgcn_global_load_lds(
        (const __attribute__((address_space(1))) unsigned int*)g,
        (__attribute__((address_space(3))) unsigned int*)l, 16, 0, 0);
}

// f32 -> bf16 pre-convert: queries (131072), keys (2097152), W1 (524288) elems.
__global__ __launch_bounds__(256) void convert_bf16(
    const float* __restrict__ q, const float* __restrict__ k,
    const float* __restrict__ w, unsigned short* __restrict__ qb,
    unsigned short* __restrict__ kb, unsigned short* __restrict__ wb)
{
    int id = blockIdx.x * 256 + threadIdx.x;
    const float* src; unsigned short* dst; int off;
    if (id < 32768)        { src = q; dst = qb; off = id; }
    else if (id < 557056)  { src = k; dst = kb; off = id - 32768; }
    else                   { src = w; dst = wb; off = id - 557056; }
    float4 v = ((const float4*)src)[off];
    ushort4 o;
    o.x = (unsigned short)f2bf(v.x); o.y = (unsigned short)f2bf(v.y);
    o.z = (unsigned short)f2bf(v.z); o.w = (unsigned short)f2bf(v.w);
    ((ushort4*)dst)[off] = o;
}

// Fused q_proj/k_proj GEMM, bf16 MFMA, global_load_lds staging.
// E[m][n] = exp2( (sum_k A[m][k]*W1[n][col_off+k] + bias[n]) * TANH_SCALE )
// blocks 0..511: k_proj -> Ek; 512..543: q_proj -> Eq. Tile 64x64, BK=64.
// LDS rows 128 B DMA-packed; XOR swizzle keeps ds_read_b128 <=2-way.
__global__ __launch_bounds__(256) void proj_mfma(
    const unsigned short* __restrict__ qb, const unsigned short* __restrict__ kb,
    const unsigned short* __restrict__ wb, const float* __restrict__ b1,
    float* __restrict__ qp, float* __restrict__ kp)
{
    __shared__ __align__(16) unsigned short As[64][64];
    __shared__ __align__(16) unsigned short Ws[64][64];

    const int bx = blockIdx.x;
    const unsigned short* A; float* C; const float* bias; int mb, nb, col_off;
    if (bx < 512) {
        A = kb; C = kp; bias = b1; col_off = 512;
        mb = (bx >> 3) * 64; nb = (bx & 7) * 64;
    } else {
        int b2 = bx - 512;
        A = qb; C = qp; bias = nullptr; col_off = 0;
        mb = (b2 >> 3) * 64; nb = (b2 & 7) * 64;
    }

    const int t = threadIdx.x;
    const int l = t & 63;
    const int wv = t >> 6;
    const int wm = (wv & 1) * 32;
    const int wn = (wv >> 1) * 32;
    const int lane16 = l & 15;
    const int quad   = l >> 4;
    const int r8   = l >> 3;
    const int schk = (l & 7) ^ r8;

    f32x4 acc[2][2] = {{{0.f,0.f,0.f,0.f},{0.f,0.f,0.f,0.f}},
                       {{0.f,0.f,0.f,0.f},{0.f,0.f,0.f,0.f}}};

    for (int kc = 0; kc < DIM; kc += 64) {
#pragma unroll
        for (int i = 0; i < 2; ++i) {
            int rbase = wv * 16 + i * 8;
            async_copy16(A + (size_t)(mb + rbase + r8) * DIM + kc + schk * 8, &As[rbase][0]);
            async_copy16(wb + (size_t)(nb + rbase + r8) * 1024 + col_off + kc + schk * 8, &Ws[rbase][0]);
        }
        __syncthreads();

#pragma unroll
        for (int ks = 0; ks < 2; ++ks) {
            int cc = ks * 4 + quad;
            int sw = (cc ^ (lane16 & 7)) << 3;
            bf16x8 a0  = *(const bf16x8*)&As[wm + lane16][sw];
            bf16x8 a1  = *(const bf16x8*)&As[wm + 16 + lane16][sw];
            bf16x8 b0  = *(const bf16x8*)&Ws[wn + lane16][sw];
            bf16x8 b1v = *(const bf16x8*)&Ws[wn + 16 + lane16][sw];
            acc[0][0] = __builtin_amdgcn_mfma_f32_16x16x32_bf16(a0, b0,  acc[0][0], 0, 0, 0);
            acc[0][1] = __builtin_amdgcn_mfma_f32_16x16x32_bf16(a0, b1v, acc[0][1], 0, 0, 0);
            acc[1][0] = __builtin_amdgcn_mfma_f32_16x16x32_bf16(a1, b0,  acc[1][0], 0, 0, 0);
            acc[1][1] = __builtin_amdgcn_mfma_f32_16x16x32_bf16(a1, b1v, acc[1][1], 0, 0, 0);
        }
        __syncthreads();
    }

#pragma unroll
    for (int mi = 0; mi < 2; ++mi) {
#pragma unroll
        for (int ni = 0; ni < 2; ++ni) {
            int col = nb + wn + 16 * ni + lane16;
            float bv = bias ? bias[col] : 0.0f;
#pragma unroll
            for (int r = 0; r < 4; ++r) {
                int row = mb + wm + 16 * mi + quad * 4 + r;
                C[(size_t)row * DIM + col] = fast_exp2((acc[mi][ni][r] + bv) * TANH_SCALE);
            }
        }
    }
}

// th[half][b,q,s] = -TANH_SCALE * sum_{h in half} w2[h]/(1 + Eq[q][h]*Ek[s][h])
// d = fma(Eq,Ek,1); paired rcp. q-row in registers (broadcast loads), w2 via
// wave-uniform s_load; only k through LDS. Tile 16q x 32s. Grid (32, 8, 4).
__global__ __launch_bounds__(256, 4) void scores_kernel(
    const float* __restrict__ qp, const float* __restrict__ kp,
    const float* __restrict__ w2, float* __restrict__ th)
{
    __shared__ __align__(16) float ks[32][68];
    const int t     = threadIdx.x;
    const int sb    = blockIdx.x * 32;
    const int qt    = blockIdx.y & 3;
    const int half  = blockIdx.y >> 2;
    const int kbase = half * 256;
    const int qrow0 = blockIdx.z * 64 + qt * 16;
    const int krow0 = blockIdx.z * 1024 + sb;
    float* thh = th + (size_t)half * 256 * SLEN;

    const int tq = t >> 4;
    const int ts = t & 15;
    const float* qrow = qp + (size_t)(qrow0 + tq) * DIM + kbase;
    const float* w2b  = w2 + kbase;
    float a00 = 0.f, a01 = 0.f, a10 = 0.f, a11 = 0.f;

    for (int kc = 0; kc < 256; kc += 64) {
#pragma unroll
        for (int rr = 0; rr < 2; ++rr) {
            int idx = t + rr * 256;
            int r = idx >> 4, g = (idx & 15) << 2;
            *(float4*)&ks[r][g] = *(const float4*)(kp + (size_t)(krow0 + r) * DIM + kbase + kc + g);
        }
        float4 qreg[16];
#pragma unroll
        for (int i = 0; i < 16; ++i)
            qreg[i] = *(const float4*)(qrow + kc + (i << 2));
        __syncthreads();
#pragma unroll
        for (int k4 = 0; k4 < 16; ++k4) {
            float4 qv = qreg[k4];
            float4 k0 = *(const float4*)&ks[ts][k4 << 2];
            float4 k1 = *(const float4*)&ks[ts + 16][k4 << 2];
            float4 wv = *(const float4*)(w2b + kc + (k4 << 2));
            {
                float d0 = fmaf(qv.x, k0.x, 1.0f);
                float d1 = fmaf(qv.y, k0.y, 1.0f);
                a00 = fmaf(fmaf(wv.x, d1, wv.y * d0), fast_rcp(d0 * d1), a00);
                float d2 = fmaf(qv.z, k0.z, 1.0f);
                float d3 = fmaf(qv.w, k0.w, 1.0f);
                a01 = fmaf(fmaf(wv.z, d3, wv.w * d2), fast_rcp(d2 * d3), a01);
            }
            {
                float d0 = fmaf(qv.x, k1.x, 1.0f);
                float d1 = fmaf(qv.y, k1.y, 1.0f);
                a10 = fmaf(fmaf(wv.x, d1, wv.y * d0), fast_rcp(d0 * d1), a10);
                float d2 = fmaf(qv.z, k1.z, 1.0f);
                float d3 = fmaf(qv.w, k1.w, 1.0f);
                a11 = fmaf(fmaf(wv.z, d3, wv.w * d2), fast_rcp(d2 * d3), a11);
            }
        }
        __syncthreads();
    }
    thh[(size_t)(qrow0 + tq) * SLEN + sb + ts]      = -TANH_SCALE * (a00 + a01);
    thh[(size_t)(qrow0 + tq) * SLEN + sb + ts + 16] = -TANH_SCALE * (a10 + a11);
}

// pt[kt][b*64+q][v] = sum over 128-s chunk of e*values, e = exp2(th0+th1)
// inline during staging (unnormalized — safe, |arg|<=35). vt==0 blocks emit
// per-(kt,row) e-sums via 8-lane shuffle. Grid (8 vt, 8 kt, 4 b).
__global__ __launch_bounds__(256) void av_gemm(
    const float* __restrict__ th, const float* __restrict__ values,
    float* __restrict__ pt, float* __restrict__ sums_p)
{
    __shared__ __align__(16) float As[32][68];
    __shared__ __align__(16) float Bs[32][68];
    const int t  = threadIdx.x;
    const int nb = blockIdx.x * 64;
    const int kt = blockIdx.y;
    const int kb = kt * 128;
    const int b  = blockIdx.z;
    const int tx = t & 15, ty = t >> 4;
    float acc[4][4] = {};
    float rsum[2] = {0.f, 0.f};
    for (int kc = 0; kc < 128; kc += 32) {
        const int k0 = kb + kc;
#pragma unroll
        for (int r = 0; r < 2; ++r) {
            int idx = t + r * 256;
            int m   = idx >> 3;
            int k4  = (idx & 7) << 2;
            size_t base = (size_t)(b * 64 + m) * SLEN + k0 + k4;
            float4 t0 = *(const float4*)(th + base);
            float4 t1 = *(const float4*)(th + 262144 + base);
            float4 e;
            e.x = fast_exp2(t0.x + t1.x);
            e.y = fast_exp2(t0.y + t1.y);
            e.z = fast_exp2(t0.z + t1.z);
            e.w = fast_exp2(t0.w + t1.w);
            As[k4 + 0][m] = e.x; As[k4 + 1][m] = e.y;
            As[k4 + 2][m] = e.z; As[k4 + 3][m] = e.w;
            rsum[r] += e.x + e.y + e.z + e.w;
            int kk = idx >> 4;
            int g  = (idx & 15) << 2;
            *(float4*)&Bs[kk][g] =
                *(const float4*)(values + (size_t)(b * 1024 + k0 + kk) * DIM + nb + g);
        }
        __syncthreads();
#pragma unroll
        for (int k = 0; k < 32; ++k) {
            float4 a  = *(const float4*)&As[k][ty << 2];
            float4 bv = *(const float4*)&Bs[k][tx << 2];
            float am[4] = {a.x, a.y, a.z, a.w};
            float bn[4] = {bv.x, bv.y, bv.z, bv.w};
#pragma unroll
            for (int i = 0; i < 4; ++i)
#pragma unroll
                for (int j = 0; j < 4; ++j)
                    acc[i][j] = fmaf(am[i], bn[j], acc[i][j]);
        }
        __syncthreads();
    }
#pragma unroll
    for (int i = 0; i < 4; ++i) {
        int row = b * 64 + (ty << 2) + i;
        float4 o;
        o.x = acc[i][0]; o.y = acc[i][1]; o.z = acc[i][2]; o.w = acc[i][3];
        *(float4*)(pt + ((size_t)kt * 256 + row) * DIM + nb + (tx << 2)) = o;
    }
    if (nb == 0) {
#pragma unroll
        for (int r = 0; r < 2; ++r) {
            float v = rsum[r];
            v += __shfl_xor(v, 1, 64);
            v += __shfl_xor(v, 2, 64);
            v += __shfl_xor(v, 4, 64);
            if ((t & 7) == 0) {
                int m = (t >> 3) + r * 32;
                sums_p[kt * 256 + b * 64 + m] = v;
            }
        }
    }
}

// out = (sum_{kt} pt[kt]) / (sum_{kt} sums_p[kt]). 32768 float4s.
__global__ __launch_bounds__(256) void reduce_kernel(
    const float* __restrict__ pt, const float* __restrict__ sums_p,
    float* __restrict__ out)
{
    int idx = blockIdx.x * 256 + threadIdx.x;
    const float4* p = (const float4*)pt;
    float4 a = p[idx];
#pragma unroll
    for (int k = 1; k < 8; ++k) {
        float4 v = p[k * 32768 + idx];
        a.x += v.x; a.y += v.y; a.z += v.z; a.w += v.w;
    }
    int row = idx >> 7;
    float s = 0.f;
#pragma unroll
    for (int k = 0; k < 8; ++k) s += sums_p[k * 256 + row];
    float r = fast_rcp(s);
    a.x *= r; a.y *= r; a.z *= r; a.w *= r;
    ((float4*)out)[idx] = a;
}

extern "C" void kernel_launch(void* const* d_in, const int* in_sizes, int n_in,
                              void* d_out, int out_size, void* d_ws, size_t ws_size,
                              hipStream_t stream) {
    const float* queries = (const float*)d_in[0];
    const float* keys    = (const float*)d_in[1];
    const float* values  = (const float*)d_in[2];
    const float* W1      = (const float*)d_in[3];
    const float* b1      = (const float*)d_in[4];
    const float* w2      = (const float*)d_in[5];
    float* out = (float*)d_out;

    float* qp     = (float*)d_ws;                   // 131072 f32 (Eq)
    float* kp     = qp + 131072;                    // 2097152 f32 (Ek)
    float* th     = kp + 2097152;                   // 2 x 262144 f32
    float* pt     = th + 2 * 262144;                // 8 x 131072 f32
    float* sums_p = pt + 8 * 131072;                // 2048 f32
    unsigned short* qbf = (unsigned short*)(sums_p + 2048);
    unsigned short* kbf = qbf + 131072;
    unsigned short* wbf = kbf + 2097152;
    (void)in_sizes; (void)n_in; (void)ws_size; (void)out_size;

    convert_bf16<<<dim3(2688), 256, 0, stream>>>(queries, keys, W1, qbf, kbf, wbf);
    proj_mfma<<<dim3(544), 256, 0, stream>>>(qbf, kbf, wbf, b1, qp, kp);
    scores_kernel<<<dim3(32, 8, 4), 256, 0, stream>>>(qp, kp, w2, th);
    av_gemm<<<dim3(8, 8, 4), 256, 0, stream>>>(th, values, pt, sums_p);
    reduce_kernel<<<dim3(128), 256, 0, stream>>>(pt, sums_p, out);
}